// Round 1
// baseline (1479.368 us; speedup 1.0000x reference)
//
#include <hip/hip_runtime.h>
#include <math.h>

#define NN 50000
#define NE 800000
#define EMB 128
#define HID 256
#define NF 7
#define EF 5
#define NL 5
#define BN_EPS 1e-5f

// ---------------------------------------------------------------------------
// k_prep: block 0 computes bias-sum vectors; all blocks zero CSR counts/cursor
// ---------------------------------------------------------------------------
__global__ void k_prep(const float* __restrict__ b_x, const float* __restrict__ b_e,
                       float* __restrict__ bsum_x, float* __restrict__ bsum_e,
                       int* __restrict__ counts, int* __restrict__ cursor) {
    int tid = threadIdx.x;
    if (blockIdx.x == 0 && tid < EMB) {
        float s = 0.f;
        for (int f = 0; f < NF; ++f) s += b_x[f * EMB + tid];
        bsum_x[tid] = s;
        for (int l = 0; l < NL; ++l) {
            float se = 0.f;
            for (int f = 0; f < EF; ++f) se += b_e[(l * EF + f) * EMB + tid];
            bsum_e[l * EMB + tid] = se;
        }
    }
    int gid = blockIdx.x * blockDim.x + tid;
    int stride = gridDim.x * blockDim.x;
    for (int i = gid; i < NN; i += stride) { counts[i] = 0; cursor[i] = 0; }
}

// ---------------------------------------------------------------------------
// k_init: h = x @ W_x + bsum_x   (32 threads/node, float4 per thread)
// ---------------------------------------------------------------------------
__global__ void k_init(const float* __restrict__ x, const float* __restrict__ W_x,
                       const float* __restrict__ bsum_x, float* __restrict__ h) {
    int gid = blockIdx.x * blockDim.x + threadIdx.x;
    int v = gid >> 5;
    if (v >= NN) return;
    int c = (gid & 31) << 2;
    float4 acc = *(const float4*)(bsum_x + c);
    #pragma unroll
    for (int f = 0; f < NF; ++f) {
        float xv = x[(size_t)v * NF + f];
        float4 w = *(const float4*)(W_x + f * EMB + c);
        acc.x += xv * w.x; acc.y += xv * w.y; acc.z += xv * w.z; acc.w += xv * w.w;
    }
    *(float4*)(h + (size_t)v * EMB + c) = acc;
}

// ---------------------------------------------------------------------------
// CSR build: histogram of dst, exclusive scan, bucket fill
// ---------------------------------------------------------------------------
__global__ void k_hist(const int* __restrict__ dst, int* __restrict__ counts) {
    int e = blockIdx.x * blockDim.x + threadIdx.x;
    if (e < NE) atomicAdd(&counts[dst[e]], 1);
}

__global__ void k_scan(const int* __restrict__ counts, int* __restrict__ row_start) {
    __shared__ int lds[1024];
    int tid = threadIdx.x;
    const int PT = (NN + 1023) / 1024;  // 49 elements per thread
    int base = tid * PT;
    int s = 0;
    for (int i = 0; i < PT; ++i) {
        int idx = base + i;
        if (idx < NN) s += counts[idx];
    }
    lds[tid] = s;
    __syncthreads();
    for (int off = 1; off < 1024; off <<= 1) {
        int val = 0;
        if (tid >= off) val = lds[tid - off];
        __syncthreads();
        if (tid >= off) lds[tid] += val;
        __syncthreads();
    }
    int run = (tid == 0) ? 0 : lds[tid - 1];
    for (int i = 0; i < PT; ++i) {
        int idx = base + i;
        if (idx < NN) {
            row_start[idx] = run;
            run += counts[idx];
        }
    }
    if (tid == 1023) row_start[NN] = lds[1023];
}

__global__ void k_fill(const int* __restrict__ src, const int* __restrict__ dst,
                       const int* __restrict__ row_start, int* __restrict__ cursor,
                       int* __restrict__ sorted_src, int* __restrict__ sorted_eid) {
    int e = blockIdx.x * blockDim.x + threadIdx.x;
    if (e >= NE) return;
    int d = dst[e];
    int pos = atomicAdd(&cursor[d], 1);
    int idx = row_start[d] + pos;
    sorted_src[idx] = src[e];
    sorted_eid[idx] = e;
}

// ---------------------------------------------------------------------------
// k_agg: agg[v] = h[v] + bsum_e + sum_{e:(s->v)} (h[s] + edge_attr[e]@W_e + bsum_e)
// One wave (64 threads) per node, float2 per thread -> no intra-wave divergence,
// 512B coalesced gathers. Block 0 also zeroes BN stats for this layer.
// ---------------------------------------------------------------------------
__global__ __launch_bounds__(256) void k_agg(
        const float* __restrict__ h, const float* __restrict__ edge_attr,
        const float* __restrict__ W_e_l, const float* __restrict__ bsum_e_l,
        const int* __restrict__ row_start, const int* __restrict__ sorted_src,
        const int* __restrict__ sorted_eid,
        float* __restrict__ agg, float* __restrict__ stats) {
    int tid = threadIdx.x;
    if (blockIdx.x == 0 && tid < 2 * EMB) stats[tid] = 0.f;
    int gid = blockIdx.x * 256 + tid;
    int v = gid >> 6;
    if (v >= NN) return;
    int c = (gid & 63) << 1;
    float2 we0 = *(const float2*)(W_e_l + 0 * EMB + c);
    float2 we1 = *(const float2*)(W_e_l + 1 * EMB + c);
    float2 we2 = *(const float2*)(W_e_l + 2 * EMB + c);
    float2 we3 = *(const float2*)(W_e_l + 3 * EMB + c);
    float2 we4 = *(const float2*)(W_e_l + 4 * EMB + c);
    float2 bs = *(const float2*)(bsum_e_l + c);
    float2 hv = *(const float2*)(h + (size_t)v * EMB + c);
    float ax = hv.x + bs.x;   // self loop: h[v] + sl_emb
    float ay = hv.y + bs.y;
    int e0 = row_start[v], e1 = row_start[v + 1];
    for (int e = e0; e < e1; ++e) {
        int s = sorted_src[e];
        int eid = sorted_eid[e];
        const float* ea = edge_attr + (size_t)eid * EF;
        float2 hs = *(const float2*)(h + (size_t)s * EMB + c);
        float a0 = ea[0], a1 = ea[1], a2 = ea[2], a3 = ea[3], a4 = ea[4];
        ax += hs.x + bs.x + a0 * we0.x + a1 * we1.x + a2 * we2.x + a3 * we3.x + a4 * we4.x;
        ay += hs.y + bs.y + a0 * we0.y + a1 * we1.y + a2 * we2.y + a3 * we3.y + a4 * we4.y;
    }
    *(float2*)(agg + (size_t)v * EMB + c) = make_float2(ax, ay);
}

// ---------------------------------------------------------------------------
// k_mlp: z = relu(io @ W1 + b1) @ W2 + b2, in-place on io (agg buffer).
// 32-row tile; phase1: thread = 8 rows x 4 hidden cols; phase2: 8 rows x 2 out
// cols. All LDS reads are wave-uniform broadcasts (rg uniform per wave).
// Accumulates per-column sum / sumsq into stats (block-reduced, then atomics).
// ---------------------------------------------------------------------------
__global__ __launch_bounds__(256) void k_mlp(
        float* io,
        const float* __restrict__ W1_l, const float* __restrict__ b1_l,
        const float* __restrict__ W2_l, const float* __restrict__ b2_l,
        float* __restrict__ stats) {
    __shared__ float lds_in[32][EMB];    // 16 KB
    __shared__ float lds_hid[32][HID];   // 32 KB
    __shared__ float lds_s[4][EMB];      // 2 KB
    __shared__ float lds_q[4][EMB];      // 2 KB
    int tid = threadIdx.x;
    int r0 = blockIdx.x * 32;
    // load input tile
    for (int i = tid; i < 32 * EMB / 4; i += 256) {
        int r = i >> 5;
        int c = (i & 31) << 2;
        int row = r0 + r;
        float4 v = (row < NN) ? *(const float4*)(io + (size_t)row * EMB + c)
                              : make_float4(0.f, 0.f, 0.f, 0.f);
        *(float4*)(&lds_in[r][c]) = v;
    }
    __syncthreads();
    int cg = tid & 63;   // col group (uniform rg per wave)
    int rg = tid >> 6;   // row group: rows 8*rg..8*rg+7
    // phase 1: hidden = relu(in @ W1 + b1)
    float acc[8][4];
    {
        float4 b = *(const float4*)(b1_l + cg * 4);
        #pragma unroll
        for (int r = 0; r < 8; ++r) { acc[r][0] = b.x; acc[r][1] = b.y; acc[r][2] = b.z; acc[r][3] = b.w; }
        for (int k4 = 0; k4 < EMB / 4; ++k4) {
            float4 w0 = *(const float4*)(W1_l + (k4 * 4 + 0) * HID + cg * 4);
            float4 w1 = *(const float4*)(W1_l + (k4 * 4 + 1) * HID + cg * 4);
            float4 w2 = *(const float4*)(W1_l + (k4 * 4 + 2) * HID + cg * 4);
            float4 w3 = *(const float4*)(W1_l + (k4 * 4 + 3) * HID + cg * 4);
            #pragma unroll
            for (int r = 0; r < 8; ++r) {
                float4 iv = *(const float4*)(&lds_in[rg * 8 + r][k4 * 4]);
                acc[r][0] += iv.x * w0.x + iv.y * w1.x + iv.z * w2.x + iv.w * w3.x;
                acc[r][1] += iv.x * w0.y + iv.y * w1.y + iv.z * w2.y + iv.w * w3.y;
                acc[r][2] += iv.x * w0.z + iv.y * w1.z + iv.z * w2.z + iv.w * w3.z;
                acc[r][3] += iv.x * w0.w + iv.y * w1.w + iv.z * w2.w + iv.w * w3.w;
            }
        }
        #pragma unroll
        for (int r = 0; r < 8; ++r)
            *(float4*)(&lds_hid[rg * 8 + r][cg * 4]) =
                make_float4(fmaxf(acc[r][0], 0.f), fmaxf(acc[r][1], 0.f),
                            fmaxf(acc[r][2], 0.f), fmaxf(acc[r][3], 0.f));
    }
    __syncthreads();
    // phase 2: z = hid @ W2 + b2 (2 out cols per thread)
    float a2[8][2];
    {
        float2 b = *(const float2*)(b2_l + cg * 2);
        #pragma unroll
        for (int r = 0; r < 8; ++r) { a2[r][0] = b.x; a2[r][1] = b.y; }
        for (int k4 = 0; k4 < HID / 4; ++k4) {
            float2 w0 = *(const float2*)(W2_l + (k4 * 4 + 0) * EMB + cg * 2);
            float2 w1 = *(const float2*)(W2_l + (k4 * 4 + 1) * EMB + cg * 2);
            float2 w2 = *(const float2*)(W2_l + (k4 * 4 + 2) * EMB + cg * 2);
            float2 w3 = *(const float2*)(W2_l + (k4 * 4 + 3) * EMB + cg * 2);
            #pragma unroll
            for (int r = 0; r < 8; ++r) {
                float4 hv = *(const float4*)(&lds_hid[rg * 8 + r][k4 * 4]);
                a2[r][0] += hv.x * w0.x + hv.y * w1.x + hv.z * w2.x + hv.w * w3.x;
                a2[r][1] += hv.x * w0.y + hv.y * w1.y + hv.z * w2.y + hv.w * w3.y;
            }
        }
    }
    float ps0 = 0.f, ps1 = 0.f, pq0 = 0.f, pq1 = 0.f;
    #pragma unroll
    for (int r = 0; r < 8; ++r) {
        int row = r0 + rg * 8 + r;
        if (row < NN) {
            *(float2*)(io + (size_t)row * EMB + cg * 2) = make_float2(a2[r][0], a2[r][1]);
            ps0 += a2[r][0]; pq0 += a2[r][0] * a2[r][0];
            ps1 += a2[r][1]; pq1 += a2[r][1] * a2[r][1];
        }
    }
    lds_s[rg][cg * 2 + 0] = ps0; lds_s[rg][cg * 2 + 1] = ps1;
    lds_q[rg][cg * 2 + 0] = pq0; lds_q[rg][cg * 2 + 1] = pq1;
    __syncthreads();
    if (tid < EMB) {
        float s = lds_s[0][tid] + lds_s[1][tid] + lds_s[2][tid] + lds_s[3][tid];
        float q = lds_q[0][tid] + lds_q[1][tid] + lds_q[2][tid] + lds_q[3][tid];
        atomicAdd(&stats[tid], s);
        atomicAdd(&stats[EMB + tid], q);
    }
}

// ---------------------------------------------------------------------------
// k_bn: z -> (z - mu) * gamma/sqrt(var+eps) + beta, optional ELU, write hout
// ---------------------------------------------------------------------------
__global__ void k_bn(const float* __restrict__ z, const float* __restrict__ stats,
                     const float* __restrict__ gamma_l, const float* __restrict__ beta_l,
                     float* __restrict__ hout, int apply_elu) {
    __shared__ float sc[EMB], sh[EMB];
    int tid = threadIdx.x;
    if (tid < EMB) {
        float mu = stats[tid] * (1.f / NN);
        float var = stats[EMB + tid] * (1.f / NN) - mu * mu;
        float s = gamma_l[tid] * rsqrtf(var + BN_EPS);
        sc[tid] = s;
        sh[tid] = beta_l[tid] - mu * s;
    }
    __syncthreads();
    int gid = blockIdx.x * blockDim.x + tid;
    if (gid >= NN * EMB / 4) return;
    int c = (gid & 31) << 2;
    float4 zv = *(const float4*)(z + (size_t)gid * 4);
    float o0 = zv.x * sc[c + 0] + sh[c + 0];
    float o1 = zv.y * sc[c + 1] + sh[c + 1];
    float o2 = zv.z * sc[c + 2] + sh[c + 2];
    float o3 = zv.w * sc[c + 3] + sh[c + 3];
    if (apply_elu) {
        o0 = (o0 > 0.f) ? o0 : (expf(o0) - 1.f);
        o1 = (o1 > 0.f) ? o1 : (expf(o1) - 1.f);
        o2 = (o2 > 0.f) ? o2 : (expf(o2) - 1.f);
        o3 = (o3 > 0.f) ? o3 : (expf(o3) - 1.f);
    }
    *(float4*)(hout + (size_t)gid * 4) = make_float4(o0, o1, o2, o3);
}

// ---------------------------------------------------------------------------
extern "C" void kernel_launch(void* const* d_in, const int* in_sizes, int n_in,
                              void* d_out, int out_size, void* d_ws, size_t ws_size,
                              hipStream_t stream) {
    const float* x         = (const float*)d_in[0];
    const float* edge_attr = (const float*)d_in[1];
    const int*   edge_idx  = (const int*)d_in[2];
    const float* W_x   = (const float*)d_in[3];
    const float* b_x   = (const float*)d_in[4];
    const float* W_e   = (const float*)d_in[5];
    const float* b_e   = (const float*)d_in[6];
    const float* W1    = (const float*)d_in[7];
    const float* b1    = (const float*)d_in[8];
    const float* W2    = (const float*)d_in[9];
    const float* b2    = (const float*)d_in[10];
    const float* gamma = (const float*)d_in[11];
    const float* beta  = (const float*)d_in[12];
    float* h = (float*)d_out;  // h lives in d_out across all layers

    const int* src = edge_idx;
    const int* dst = edge_idx + NE;

    char* p = (char*)d_ws;
    auto alloc = [&](size_t bytes) { char* q = p; p += (bytes + 255) & ~(size_t)255; return q; };
    float* agg        = (float*)alloc((size_t)NN * EMB * sizeof(float));  // also holds z in-place
    int*   row_start  = (int*)alloc((NN + 1) * sizeof(int));
    int*   counts     = (int*)alloc(NN * sizeof(int));
    int*   cursor     = (int*)alloc(NN * sizeof(int));
    int*   sorted_src = (int*)alloc(NE * sizeof(int));
    int*   sorted_eid = (int*)alloc(NE * sizeof(int));
    float* stats      = (float*)alloc(2 * EMB * sizeof(float));
    float* bsum_x     = (float*)alloc(EMB * sizeof(float));
    float* bsum_e     = (float*)alloc(NL * EMB * sizeof(float));

    k_prep<<<256, 256, 0, stream>>>(b_x, b_e, bsum_x, bsum_e, counts, cursor);
    k_init<<<(NN * 32) / 256, 256, 0, stream>>>(x, W_x, bsum_x, h);
    k_hist<<<(NE + 255) / 256, 256, 0, stream>>>(dst, counts);
    k_scan<<<1, 1024, 0, stream>>>(counts, row_start);
    k_fill<<<(NE + 255) / 256, 256, 0, stream>>>(src, dst, row_start, cursor,
                                                 sorted_src, sorted_eid);
    for (int l = 0; l < NL; ++l) {
        k_agg<<<(NN * 64 + 255) / 256, 256, 0, stream>>>(
            h, edge_attr, W_e + (size_t)l * EF * EMB, bsum_e + l * EMB,
            row_start, sorted_src, sorted_eid, agg, stats);
        k_mlp<<<(NN + 31) / 32, 256, 0, stream>>>(
            agg, W1 + (size_t)l * EMB * HID, b1 + l * HID,
            W2 + (size_t)l * HID * EMB, b2 + l * EMB, stats);
        k_bn<<<(NN * EMB / 4 + 255) / 256, 256, 0, stream>>>(
            agg, stats, gamma + l * EMB, beta + l * EMB, h, (l < NL - 1) ? 1 : 0);
    }
}